// Round 1
// baseline (2552.656 us; speedup 1.0000x reference)
//
#include <hip/hip_runtime.h>
#include <stdint.h>

#define HID 256
#define NMAXPIX (1025 * 1025)

// ---------------- MLP eval (matches reference arithmetic closely) ----------------
__device__ __forceinline__ float mlp_eval(float wx, float wy,
                                          const float* sw1, const float* sb1,
                                          const float* sw2, float b2v) {
    const float C0 = (float)(0.5 / 1025.0);
    float cx = wx / 1025.0f + C0;
    float cy = wy / 1025.0f + C0;
    float px = cx * 2.0f - 1.0f;
    float py = cy * 2.0f - 1.0f;
    float a0 = 0.f, a1 = 0.f;
#pragma unroll 4
    for (int j = 0; j < HID; j += 2) {
        float h0 = px * sw1[j]     + py * sw1[HID + j]     + sb1[j];
        float h1 = px * sw1[j + 1] + py * sw1[HID + j + 1] + sb1[j + 1];
        h0 = h0 > 0.f ? h0 : 0.f;
        h1 = h1 > 0.f ? h1 : 0.f;
        a0 += h0 * sw2[j];
        a1 += h1 * sw2[j + 1];
    }
    float x = (a0 + a1) + b2v;
    float r;
    if (x >= 0.f) { r = 1.0f / (1.0f + expf(-x)); }
    else { float e = expf(x); r = e / (1.0f + e); }
    return r;
}

// ---------------- stage 0: dense 65x65 eval ----------------
__global__ __launch_bounds__(256) void k_eval0(const float* __restrict__ w1, const float* __restrict__ b1,
                                               const float* __restrict__ w2, const float* __restrict__ b2,
                                               float* __restrict__ occ) {
    __shared__ float sw1[2 * HID], sb1[HID], sw2[HID];
    int tid = threadIdx.x;
    for (int i = tid; i < 2 * HID; i += 256) sw1[i] = w1[i];
    sb1[tid] = b1[tid];
    sw2[tid] = w2[tid];
    __syncthreads();
    int n = blockIdx.x * 256 + tid;
    if (n >= 65 * 65) return;
    int i = n / 65, j = n % 65;
    occ[n] = mlp_eval(16.0f * (float)j, 16.0f * (float)i, sw1, sb1, sw2, b2[0]);
}

// ---------------- upsample 2x (bitwise dyadic averages) + key + 11-bit msb hist ----------------
__global__ __launch_bounds__(256) void k_upkey(const float* __restrict__ in, int rp,
                                               float* __restrict__ out, int r,
                                               uint32_t* __restrict__ keys,
                                               uint32_t* __restrict__ histA) {
    __shared__ uint32_t hist[2048];
    int tid = threadIdx.x;
    for (int k = tid; k < 2048; k += 256) hist[k] = 0;
    __syncthreads();
    int n = blockIdx.x * 256 + tid;
    int N = r * r;
    bool act = n < N;
    uint32_t key = 0;
    if (act) {
        int i = n / r, j = n % r;
        int i2 = i >> 1, j2 = j >> 1;
        float v;
        if ((i & 1) == 0) {
            if ((j & 1) == 0) {
                v = in[i2 * rp + j2];
            } else {
                float a = in[i2 * rp + j2], b = in[i2 * rp + j2 + 1];
                v = a * 0.5f + b * 0.5f;
            }
        } else {
            if ((j & 1) == 0) {
                float a = in[i2 * rp + j2], b = in[(i2 + 1) * rp + j2];
                v = a * 0.5f + b * 0.5f;
            } else {
                float a = in[i2 * rp + j2],     c = in[i2 * rp + j2 + 1];
                float b = in[(i2 + 1) * rp + j2], d = in[(i2 + 1) * rp + j2 + 1];
                float t1 = a * 0.5f + b * 0.5f;
                float t2 = c * 0.5f + d * 0.5f;
                v = t1 * 0.5f + t2 * 0.5f;
            }
        }
        out[n] = v;
        float unc = -fabsf(v - 0.5f);
        uint32_t u = __float_as_uint(unc);
        key = (u & 0x80000000u) ? ~u : (u | 0x80000000u);
        keys[n] = key;
    }
    // wave-aggregated LDS histogram (kills -0.5 plateau contention)
    uint32_t bin = key >> 21;
    unsigned long long m = __ballot(act);
    if (m) {
        int leader = __ffsll(m) - 1;
        uint32_t lbin = (uint32_t)__shfl((int)bin, leader, 64);
        unsigned long long sm = __ballot(act && bin == lbin);
        int lane = tid & 63;
        if (sm == m) {
            if (lane == leader) atomicAdd(&hist[lbin], (uint32_t)__popcll(m));
        } else if (act) {
            atomicAdd(&hist[bin], 1u);
        }
    }
    __syncthreads();
    for (int k = tid; k < 2048; k += 256) {
        uint32_t c = hist[k];
        if (c) atomicAdd(&histA[k], c);
    }
}

// ---------------- block exclusive scan helper (256 threads) ----------------
__device__ __forceinline__ uint32_t block_exscan_256(uint32_t v, volatile uint32_t* lds4) {
    int lane = threadIdx.x & 63, w = threadIdx.x >> 6;
    uint32_t inc = v;
#pragma unroll
    for (int d = 1; d < 64; d <<= 1) {
        uint32_t o = (uint32_t)__shfl_up((int)inc, d, 64);
        if (lane >= d) inc += o;
    }
    if (lane == 63) lds4[w] = inc;
    __syncthreads();
    uint32_t woff = 0;
    for (int i = 0; i < w; ++i) woff += lds4[i];
    return woff + inc - v;
}

// ---------------- radix-select scan pass (1 block): find digit containing the k-th largest ----------------
// scal layout: [0]=prefix [1]=rem [2]=K [3]=t
__global__ __launch_bounds__(256) void k_scan(const uint32_t* __restrict__ hist, int NB,
                                              uint32_t* __restrict__ scal,
                                              int first, uint32_t npt, int shift, int last) {
    __shared__ uint32_t lds4[4];
    int tid = threadIdx.x;
    uint32_t rem    = first ? npt : scal[1];
    uint32_t prefix = first ? 0u  : scal[0];
    int C = NB >> 8;  // bins per thread (8 or 4)
    uint32_t cnts[8];
    uint32_t s = 0;
    for (int k = 0; k < C; ++k) {
        int rb = tid * C + k;            // reversed bin index (descending value order)
        cnts[k] = hist[NB - 1 - rb];
        s += cnts[k];
    }
    uint32_t excl = block_exscan_256(s, lds4);  // contains __syncthreads (reads of scal happen before)
    uint32_t run = excl;
    for (int k = 0; k < C; ++k) {
        uint32_t c = cnts[k];
        if (rem > run && rem <= run + c) {
            uint32_t bin = (uint32_t)(NB - 1 - (tid * C + k));
            uint32_t npfx = (prefix << shift) | bin;
            uint32_t nrem = rem - run;
            if (last) { scal[2] = npfx; scal[3] = nrem; }
            else      { scal[0] = npfx; scal[1] = nrem; }
        }
        run += c;
    }
}

// ---------------- filtered histogram for radix passes 2,3 (global atomics, wave-aggregated) ----------------
__global__ __launch_bounds__(256) void k_hist_f(const uint32_t* __restrict__ keys, int N,
                                                const uint32_t* __restrict__ scal,
                                                uint32_t* __restrict__ hist,
                                                int fshift, int bshift, uint32_t bmask) {
    int n = blockIdx.x * 256 + threadIdx.x;
    uint32_t prefix = scal[0];
    bool flt = false;
    uint32_t bin = 0;
    if (n < N) {
        uint32_t key = keys[n];
        flt = (key >> fshift) == prefix;
        bin = (key >> bshift) & bmask;
    }
    unsigned long long m = __ballot(flt);
    if (!m) return;
    int leader = __ffsll(m) - 1;
    uint32_t lbin = (uint32_t)__shfl((int)bin, leader, 64);
    unsigned long long sm = __ballot(flt && bin == lbin);
    int lane = threadIdx.x & 63;
    if (sm == m) {
        if (lane == leader) atomicAdd(&hist[lbin], (uint32_t)__popcll(m));
    } else if (flt) {
        atomicAdd(&hist[bin], 1u);
    }
}

// ---------------- per-block tie counts (contiguous chunks, index order) ----------------
__global__ __launch_bounds__(256) void k_tiecnt(const uint32_t* __restrict__ keys, int N,
                                                const uint32_t* __restrict__ scal,
                                                uint32_t* __restrict__ bcnt, int chunk) {
    __shared__ uint32_t wsum[4];
    uint32_t K = scal[2];
    int base = blockIdx.x * chunk;
    int tid = threadIdx.x, lane = tid & 63, w = tid >> 6;
    uint32_t cnt = 0;
    for (int i = 0; i < chunk; i += 256) {
        int n = base + i + tid;
        if (n < N && keys[n] == K) cnt++;
    }
#pragma unroll
    for (int d = 32; d; d >>= 1) cnt += (uint32_t)__shfl_down((int)cnt, d, 64);
    if (lane == 0) wsum[w] = cnt;
    __syncthreads();
    if (tid == 0) bcnt[blockIdx.x] = wsum[0] + wsum[1] + wsum[2] + wsum[3];
}

// ---------------- exclusive scan of block tie counts (nb <= 512) ----------------
__global__ __launch_bounds__(256) void k_tiescan(const uint32_t* __restrict__ bcnt,
                                                 uint32_t* __restrict__ boff, int nb) {
    __shared__ uint32_t ldsA[4], ldsB[4];
    __shared__ uint32_t totA_s;
    int tid = threadIdx.x;
    uint32_t a = (tid < nb) ? bcnt[tid] : 0u;
    uint32_t b = (tid + 256 < nb) ? bcnt[tid + 256] : 0u;
    uint32_t ea = block_exscan_256(a, ldsA);
    if (tid == 255) totA_s = ea + a;
    __syncthreads();
    uint32_t eb = block_exscan_256(b, ldsB);
    __syncthreads();
    uint32_t totA = totA_s;
    if (tid < nb) boff[tid] = ea;
    if (tid + 256 < nb) boff[tid + 256] = totA + eb;
}

// ---------------- final: select (exact top-k w/ index-ascending ties) + MLP re-eval + scatter ----------------
__global__ __launch_bounds__(256) void k_final(const uint32_t* __restrict__ keys, int N, int r, float stride,
                                               const uint32_t* __restrict__ scal,
                                               const uint32_t* __restrict__ boff,
                                               float* __restrict__ occ,
                                               const float* __restrict__ w1, const float* __restrict__ b1,
                                               const float* __restrict__ w2, const float* __restrict__ b2,
                                               int chunk) {
    __shared__ float sw1[2 * HID], sb1[HID], sw2[HID];
    __shared__ uint32_t iterw[4];
    int tid = threadIdx.x;
    for (int i = tid; i < 2 * HID; i += 256) sw1[i] = w1[i];
    sb1[tid] = b1[tid];
    sw2[tid] = w2[tid];
    __syncthreads();
    uint32_t K = scal[2], t = scal[3];
    float vb2 = b2[0];
    int lane = tid & 63, w = tid >> 6;
    uint32_t running = boff[blockIdx.x];
    int base = blockIdx.x * chunk;
    for (int i = 0; i < chunk; i += 256) {
        int n = base + i + tid;
        bool inb = n < N;
        uint32_t key = inb ? keys[n] : 0u;
        bool tie = inb && (key == K);
        unsigned long long m = __ballot(tie);
        if (lane == 0) iterw[w] = (uint32_t)__popcll(m);
        __syncthreads();
        uint32_t mybase = running;
        for (int ww = 0; ww < w; ++ww) mybase += iterw[ww];
        uint32_t tot = iterw[0] + iterw[1] + iterw[2] + iterw[3];
        uint32_t rank = mybase + (uint32_t)__popcll(m & ((1ull << lane) - 1ull));
        bool sel = inb && ((key > K) || (tie && rank < t));
        if (sel) {
            int pi = n / r, pj = n % r;
            occ[n] = mlp_eval(stride * (float)pj, stride * (float)pi, sw1, sb1, sw2, vb2);
        }
        running += tot;
        __syncthreads();
    }
}

// ---------------- broadcast batch-0 grid to all 8 batches ----------------
__global__ __launch_bounds__(256) void k_bcast(const float* __restrict__ src, float* __restrict__ dst, int N) {
    int n = blockIdx.x * 256 + threadIdx.x;
    if (n >= N) return;
    float v = src[n];
#pragma unroll
    for (int k = 0; k < 8; ++k) dst[(size_t)k * N + n] = v;
}

extern "C" void kernel_launch(void* const* d_in, const int* in_sizes, int n_in,
                              void* d_out, int out_size, void* d_ws, size_t ws_size,
                              hipStream_t stream) {
    const float* w1 = (const float*)d_in[0];
    const float* b1 = (const float*)d_in[1];
    const float* w2 = (const float*)d_in[2];
    const float* b2 = (const float*)d_in[3];
    float* out = (float*)d_out;

    const size_t A = (((size_t)NMAXPIX * 4) + 255) & ~(size_t)255;  // one grid buffer, 256B aligned
    const size_t SMALL_BYTES = 4 * 8192 * 4;                         // 4 stages x 8192 u32
    const size_t need = 3 * A + SMALL_BYTES;

    char* base = (ws_size >= need) ? (char*)d_ws : (char*)d_out;  // d_out is 33.6MB >= 12.8MB needed
    float* buf0 = (float*)(base);
    float* buf1 = (float*)(base + A);
    uint32_t* keys = (uint32_t*)(base + 2 * A);
    uint32_t* smallb = (uint32_t*)(base + 3 * A);

    hipMemsetAsync(smallb, 0, SMALL_BYTES, stream);

    // stage 0
    k_eval0<<<dim3((65 * 65 + 255) / 256), dim3(256), 0, stream>>>(w1, b1, w2, b2, buf0);

    const int res[5]  = {65, 129, 257, 513, 1025};
    const int npts[5] = {0, 4096, 16384, 65536, 262144};
    float* cur = buf0;
    float* nxt = buf1;
    for (int s = 1; s < 5; ++s) {
        int rp = res[s - 1], r = res[s];
        int N = r * r;
        uint32_t npt = (uint32_t)npts[s];
        uint32_t* sm    = smallb + (size_t)(s - 1) * 8192;
        uint32_t* histA = sm;
        uint32_t* histB = sm + 2048;
        uint32_t* histC = sm + 4096;
        uint32_t* scal  = sm + 5120;
        uint32_t* bcnt  = sm + 5632;
        uint32_t* boff  = sm + 6144;
        int nb1 = (N + 255) / 256;
        const int chunk = 4096;
        int nb2 = (N + chunk - 1) / chunk;  // <= 257
        float stride = 1024.0f / (float)(r - 1);

        k_upkey<<<dim3(nb1), dim3(256), 0, stream>>>(cur, rp, nxt, r, keys, histA);
        k_scan<<<dim3(1), dim3(256), 0, stream>>>(histA, 2048, scal, 1, npt, 0, 0);
        k_hist_f<<<dim3(nb1), dim3(256), 0, stream>>>(keys, N, scal, histB, 21, 10, 0x7FFu);
        k_scan<<<dim3(1), dim3(256), 0, stream>>>(histB, 2048, scal, 0, 0u, 11, 0);
        k_hist_f<<<dim3(nb1), dim3(256), 0, stream>>>(keys, N, scal, histC, 10, 0, 0x3FFu);
        k_scan<<<dim3(1), dim3(256), 0, stream>>>(histC, 1024, scal, 0, 0u, 10, 1);
        k_tiecnt<<<dim3(nb2), dim3(256), 0, stream>>>(keys, N, scal, bcnt, chunk);
        k_tiescan<<<dim3(1), dim3(256), 0, stream>>>(bcnt, boff, nb2);
        k_final<<<dim3(nb2), dim3(256), 0, stream>>>(keys, N, r, stride, scal, boff, nxt,
                                                     w1, b1, w2, b2, chunk);
        float* tmp = cur; cur = nxt; nxt = tmp;
    }
    // after 4 swaps cur == buf0 (d_out offset 0 in fallback mode — bcast is read-before-write safe per thread)
    k_bcast<<<dim3((NMAXPIX + 255) / 256), dim3(256), 0, stream>>>(cur, out, NMAXPIX);
}

// Round 2
// 607.024 us; speedup vs baseline: 4.2052x; 4.2052x over previous
//
#include <hip/hip_runtime.h>
#include <stdint.h>

#define HID 256
#define NMAXPIX (1025 * 1025)
#define NREP 32   // histogram replicas (kills same-address atomic serialization)

// per-stage small-buffer layout (u32 units)
#define HISTA_OFF 0                       // 2048*32
#define HISTB_OFF 65536                   // 2048*32
#define HISTC_OFF 131072                  // 1024*32
#define SCAL_OFF  163840                  // 4 (padded 512)
#define BCNT_OFF  164352                  // 512
#define BOFF_OFF  164864                  // 512
#define STAGE_U32 165376

// ---------------- MLP eval (matches reference arithmetic closely) ----------------
__device__ __forceinline__ float mlp_eval(float wx, float wy,
                                          const float* sw1, const float* sb1,
                                          const float* sw2, float b2v) {
    const float C0 = (float)(0.5 / 1025.0);
    float cx = wx / 1025.0f + C0;
    float cy = wy / 1025.0f + C0;
    float px = cx * 2.0f - 1.0f;
    float py = cy * 2.0f - 1.0f;
    float a0 = 0.f, a1 = 0.f;
#pragma unroll 4
    for (int j = 0; j < HID; j += 2) {
        float h0 = px * sw1[j]     + py * sw1[HID + j]     + sb1[j];
        float h1 = px * sw1[j + 1] + py * sw1[HID + j + 1] + sb1[j + 1];
        h0 = h0 > 0.f ? h0 : 0.f;
        h1 = h1 > 0.f ? h1 : 0.f;
        a0 += h0 * sw2[j];
        a1 += h1 * sw2[j + 1];
    }
    float x = (a0 + a1) + b2v;
    float r;
    if (x >= 0.f) { r = 1.0f / (1.0f + expf(-x)); }
    else { float e = expf(x); r = e / (1.0f + e); }
    return r;
}

// ---------------- stage 0: dense 65x65 eval ----------------
__global__ __launch_bounds__(256) void k_eval0(const float* __restrict__ w1, const float* __restrict__ b1,
                                               const float* __restrict__ w2, const float* __restrict__ b2,
                                               float* __restrict__ occ) {
    __shared__ float sw1[2 * HID], sb1[HID], sw2[HID];
    int tid = threadIdx.x;
    for (int i = tid; i < 2 * HID; i += 256) sw1[i] = w1[i];
    sb1[tid] = b1[tid];
    sw2[tid] = w2[tid];
    __syncthreads();
    int n = blockIdx.x * 256 + tid;
    if (n >= 65 * 65) return;
    int i = n / 65, j = n % 65;
    occ[n] = mlp_eval(16.0f * (float)j, 16.0f * (float)i, sw1, sb1, sw2, b2[0]);
}

// ---------------- upsample 2x (bitwise dyadic averages) + key + 11-bit msb hist ----------------
__global__ __launch_bounds__(256) void k_upkey(const float* __restrict__ in, int rp,
                                               float* __restrict__ out, int r,
                                               uint32_t* __restrict__ keys,
                                               uint32_t* __restrict__ histA) {
    __shared__ uint32_t hist[2048];
    int tid = threadIdx.x;
    for (int k = tid; k < 2048; k += 256) hist[k] = 0;
    __syncthreads();
    int n = blockIdx.x * 256 + tid;
    int N = r * r;
    bool act = n < N;
    uint32_t key = 0;
    if (act) {
        int i = n / r, j = n % r;
        int i2 = i >> 1, j2 = j >> 1;
        float v;
        if ((i & 1) == 0) {
            if ((j & 1) == 0) {
                v = in[i2 * rp + j2];
            } else {
                float a = in[i2 * rp + j2], b = in[i2 * rp + j2 + 1];
                v = a * 0.5f + b * 0.5f;
            }
        } else {
            if ((j & 1) == 0) {
                float a = in[i2 * rp + j2], b = in[(i2 + 1) * rp + j2];
                v = a * 0.5f + b * 0.5f;
            } else {
                float a = in[i2 * rp + j2],     c = in[i2 * rp + j2 + 1];
                float b = in[(i2 + 1) * rp + j2], d = in[(i2 + 1) * rp + j2 + 1];
                float t1 = a * 0.5f + b * 0.5f;
                float t2 = c * 0.5f + d * 0.5f;
                v = t1 * 0.5f + t2 * 0.5f;
            }
        }
        out[n] = v;
        float unc = -fabsf(v - 0.5f);
        uint32_t u = __float_as_uint(unc);
        key = (u & 0x80000000u) ? ~u : (u | 0x80000000u);
        keys[n] = key;
    }
    // wave-aggregated LDS histogram (kills -0.5 plateau contention)
    uint32_t bin = key >> 21;
    unsigned long long m = __ballot(act);
    if (m) {
        int leader = __ffsll(m) - 1;
        uint32_t lbin = (uint32_t)__shfl((int)bin, leader, 64);
        unsigned long long sm = __ballot(act && bin == lbin);
        int lane = tid & 63;
        if (sm == m) {
            if (lane == leader) atomicAdd(&hist[lbin], (uint32_t)__popcll(m));
        } else if (act) {
            atomicAdd(&hist[bin], 1u);
        }
    }
    __syncthreads();
    int rep = blockIdx.x & (NREP - 1);
    for (int k = tid; k < 2048; k += 256) {
        uint32_t c = hist[k];
        if (c) atomicAdd(&histA[k * NREP + rep], c);
    }
}

// ---------------- block exclusive scan helper (256 threads) ----------------
__device__ __forceinline__ uint32_t block_exscan_256(uint32_t v, volatile uint32_t* lds4) {
    int lane = threadIdx.x & 63, w = threadIdx.x >> 6;
    uint32_t inc = v;
#pragma unroll
    for (int d = 1; d < 64; d <<= 1) {
        uint32_t o = (uint32_t)__shfl_up((int)inc, d, 64);
        if (lane >= d) inc += o;
    }
    if (lane == 63) lds4[w] = inc;
    __syncthreads();
    uint32_t woff = 0;
    for (int i = 0; i < w; ++i) woff += lds4[i];
    return woff + inc - v;
}

// ---------------- radix-select scan pass (1 block): find digit containing the k-th largest ----------------
// scal layout: [0]=prefix [1]=rem [2]=K [3]=t
__global__ __launch_bounds__(256) void k_scan(const uint32_t* __restrict__ hist, int NB,
                                              uint32_t* __restrict__ scal,
                                              int first, uint32_t npt, int shift, int last) {
    __shared__ uint32_t lds4[4];
    int tid = threadIdx.x;
    uint32_t rem    = first ? npt : scal[1];
    uint32_t prefix = first ? 0u  : scal[0];
    int C = NB >> 8;  // bins per thread (8 or 4)
    uint32_t cnts[8];
    uint32_t s = 0;
    for (int k = 0; k < C; ++k) {
        int rb = tid * C + k;            // reversed bin index (descending value order)
        int bin = NB - 1 - rb;
        const uint4* p = (const uint4*)(hist + (size_t)bin * NREP);
        uint32_t c = 0;
#pragma unroll
        for (int q = 0; q < NREP / 4; ++q) {
            uint4 v = p[q];
            c += v.x + v.y + v.z + v.w;
        }
        cnts[k] = c;
        s += c;
    }
    uint32_t excl = block_exscan_256(s, lds4);  // contains __syncthreads (reads of scal happen before)
    uint32_t run = excl;
    for (int k = 0; k < C; ++k) {
        uint32_t c = cnts[k];
        if (rem > run && rem <= run + c) {
            uint32_t bin = (uint32_t)(NB - 1 - (tid * C + k));
            uint32_t npfx = (prefix << shift) | bin;
            uint32_t nrem = rem - run;
            if (last) { scal[2] = npfx; scal[3] = nrem; }
            else      { scal[0] = npfx; scal[1] = nrem; }
        }
        run += c;
    }
}

// ---------------- filtered histogram passes 2,3: LDS hist + replicated flush ----------------
__global__ __launch_bounds__(256) void k_hist_f(const uint32_t* __restrict__ keys, int N,
                                                const uint32_t* __restrict__ scal,
                                                uint32_t* __restrict__ hist,
                                                int fshift, int bshift, uint32_t bmask) {
    __shared__ uint32_t lh[2048];
    int tid = threadIdx.x;
    for (int k = tid; k < 2048; k += 256) lh[k] = 0;
    uint32_t prefix = scal[0];
    __syncthreads();
    int stride = gridDim.x * 256;
    int lane = tid & 63;
    for (int base = blockIdx.x * 256; base < N; base += stride) {
        int n = base + tid;
        bool inb = n < N;
        uint32_t key = inb ? keys[n] : 0u;
        bool flt = inb && ((key >> fshift) == prefix);
        uint32_t bin = (key >> bshift) & bmask;
        unsigned long long m = __ballot(flt);
        if (m) {
            int leader = __ffsll(m) - 1;
            uint32_t lbin = (uint32_t)__shfl((int)bin, leader, 64);
            unsigned long long sm = __ballot(flt && bin == lbin);
            if (sm == m) {
                if (lane == leader) atomicAdd(&lh[lbin], (uint32_t)__popcll(m));
            } else if (flt) {
                atomicAdd(&lh[bin], 1u);
            }
        }
    }
    __syncthreads();
    int rep = blockIdx.x & (NREP - 1);
    for (int k = tid; k < 2048; k += 256) {
        uint32_t c = lh[k];
        if (c) atomicAdd(&hist[k * NREP + rep], c);
    }
}

// ---------------- per-block tie counts (contiguous chunks, index order) ----------------
__global__ __launch_bounds__(256) void k_tiecnt(const uint32_t* __restrict__ keys, int N,
                                                const uint32_t* __restrict__ scal,
                                                uint32_t* __restrict__ bcnt, int chunk) {
    __shared__ uint32_t wsum[4];
    uint32_t K = scal[2];
    int base = blockIdx.x * chunk;
    int tid = threadIdx.x, lane = tid & 63, w = tid >> 6;
    uint32_t cnt = 0;
    for (int i = 0; i < chunk; i += 256) {
        int n = base + i + tid;
        if (n < N && keys[n] == K) cnt++;
    }
#pragma unroll
    for (int d = 32; d; d >>= 1) cnt += (uint32_t)__shfl_down((int)cnt, d, 64);
    if (lane == 0) wsum[w] = cnt;
    __syncthreads();
    if (tid == 0) bcnt[blockIdx.x] = wsum[0] + wsum[1] + wsum[2] + wsum[3];
}

// ---------------- exclusive scan of block tie counts (nb <= 512) ----------------
__global__ __launch_bounds__(256) void k_tiescan(const uint32_t* __restrict__ bcnt,
                                                 uint32_t* __restrict__ boff, int nb) {
    __shared__ uint32_t ldsA[4], ldsB[4];
    __shared__ uint32_t totA_s;
    int tid = threadIdx.x;
    uint32_t a = (tid < nb) ? bcnt[tid] : 0u;
    uint32_t b = (tid + 256 < nb) ? bcnt[tid + 256] : 0u;
    uint32_t ea = block_exscan_256(a, ldsA);
    if (tid == 255) totA_s = ea + a;
    __syncthreads();
    uint32_t eb = block_exscan_256(b, ldsB);
    __syncthreads();
    uint32_t totA = totA_s;
    if (tid < nb) boff[tid] = ea;
    if (tid + 256 < nb) boff[tid + 256] = totA + eb;
}

// ---------------- final: select (exact top-k w/ index-ascending ties) + MLP re-eval + scatter ----------------
__global__ __launch_bounds__(256) void k_final(const uint32_t* __restrict__ keys, int N, int r, float stride,
                                               const uint32_t* __restrict__ scal,
                                               const uint32_t* __restrict__ boff,
                                               float* __restrict__ occ,
                                               const float* __restrict__ w1, const float* __restrict__ b1,
                                               const float* __restrict__ w2, const float* __restrict__ b2,
                                               int chunk) {
    __shared__ float sw1[2 * HID], sb1[HID], sw2[HID];
    __shared__ uint32_t iterw[4];
    int tid = threadIdx.x;
    for (int i = tid; i < 2 * HID; i += 256) sw1[i] = w1[i];
    sb1[tid] = b1[tid];
    sw2[tid] = w2[tid];
    __syncthreads();
    uint32_t K = scal[2], t = scal[3];
    float vb2 = b2[0];
    int lane = tid & 63, w = tid >> 6;
    uint32_t running = boff[blockIdx.x];
    int base = blockIdx.x * chunk;
    for (int i = 0; i < chunk; i += 256) {
        int n = base + i + tid;
        bool inb = n < N;
        uint32_t key = inb ? keys[n] : 0u;
        bool tie = inb && (key == K);
        unsigned long long m = __ballot(tie);
        if (lane == 0) iterw[w] = (uint32_t)__popcll(m);
        __syncthreads();
        uint32_t mybase = running;
        for (int ww = 0; ww < w; ++ww) mybase += iterw[ww];
        uint32_t tot = iterw[0] + iterw[1] + iterw[2] + iterw[3];
        uint32_t rank = mybase + (uint32_t)__popcll(m & ((1ull << lane) - 1ull));
        bool sel = inb && ((key > K) || (tie && rank < t));
        if (sel) {
            int pi = n / r, pj = n % r;
            occ[n] = mlp_eval(stride * (float)pj, stride * (float)pi, sw1, sb1, sw2, vb2);
        }
        running += tot;
        __syncthreads();
    }
}

// ---------------- broadcast batch-0 grid to all 8 batches ----------------
__global__ __launch_bounds__(256) void k_bcast(const float* __restrict__ src, float* __restrict__ dst, int N) {
    int n = blockIdx.x * 256 + threadIdx.x;
    if (n >= N) return;
    float v = src[n];
#pragma unroll
    for (int k = 0; k < 8; ++k) dst[(size_t)k * N + n] = v;
}

extern "C" void kernel_launch(void* const* d_in, const int* in_sizes, int n_in,
                              void* d_out, int out_size, void* d_ws, size_t ws_size,
                              hipStream_t stream) {
    const float* w1 = (const float*)d_in[0];
    const float* b1 = (const float*)d_in[1];
    const float* w2 = (const float*)d_in[2];
    const float* b2 = (const float*)d_in[3];
    float* out = (float*)d_out;

    const size_t A = (((size_t)NMAXPIX * 4) + 255) & ~(size_t)255;  // one grid buffer, 256B aligned
    const size_t SMALL_BYTES = (size_t)4 * STAGE_U32 * 4;            // 4 stages
    const size_t need = 3 * A + SMALL_BYTES;

    char* base = (ws_size >= need) ? (char*)d_ws : (char*)d_out;  // d_out is 33.6MB >= ~15.3MB needed
    float* buf0 = (float*)(base);
    float* buf1 = (float*)(base + A);
    uint32_t* keys = (uint32_t*)(base + 2 * A);
    uint32_t* smallb = (uint32_t*)(base + 3 * A);

    hipMemsetAsync(smallb, 0, SMALL_BYTES, stream);

    // stage 0
    k_eval0<<<dim3((65 * 65 + 255) / 256), dim3(256), 0, stream>>>(w1, b1, w2, b2, buf0);

    const int res[5]  = {65, 129, 257, 513, 1025};
    const int npts[5] = {0, 4096, 16384, 65536, 262144};
    float* cur = buf0;
    float* nxt = buf1;
    for (int s = 1; s < 5; ++s) {
        int rp = res[s - 1], r = res[s];
        int N = r * r;
        uint32_t npt = (uint32_t)npts[s];
        uint32_t* sm    = smallb + (size_t)(s - 1) * STAGE_U32;
        uint32_t* histA = sm + HISTA_OFF;
        uint32_t* histB = sm + HISTB_OFF;
        uint32_t* histC = sm + HISTC_OFF;
        uint32_t* scal  = sm + SCAL_OFF;
        uint32_t* bcnt  = sm + BCNT_OFF;
        uint32_t* boff  = sm + BOFF_OFF;
        int nb1 = (N + 255) / 256;
        int nbh = nb1 < 512 ? nb1 : 512;
        const int chunk = 4096;
        int nb2 = (N + chunk - 1) / chunk;  // <= 257
        float stride = 1024.0f / (float)(r - 1);

        k_upkey<<<dim3(nb1), dim3(256), 0, stream>>>(cur, rp, nxt, r, keys, histA);
        k_scan<<<dim3(1), dim3(256), 0, stream>>>(histA, 2048, scal, 1, npt, 0, 0);
        k_hist_f<<<dim3(nbh), dim3(256), 0, stream>>>(keys, N, scal, histB, 21, 10, 0x7FFu);
        k_scan<<<dim3(1), dim3(256), 0, stream>>>(histB, 2048, scal, 0, 0u, 11, 0);
        k_hist_f<<<dim3(nbh), dim3(256), 0, stream>>>(keys, N, scal, histC, 10, 0, 0x3FFu);
        k_scan<<<dim3(1), dim3(256), 0, stream>>>(histC, 1024, scal, 0, 0u, 10, 1);
        k_tiecnt<<<dim3(nb2), dim3(256), 0, stream>>>(keys, N, scal, bcnt, chunk);
        k_tiescan<<<dim3(1), dim3(256), 0, stream>>>(bcnt, boff, nb2);
        k_final<<<dim3(nb2), dim3(256), 0, stream>>>(keys, N, r, stride, scal, boff, nxt,
                                                     w1, b1, w2, b2, chunk);
        float* tmp = cur; cur = nxt; nxt = tmp;
    }
    // after 4 swaps cur == buf0 (d_out offset 0 in fallback mode — bcast is read-before-write safe per thread)
    k_bcast<<<dim3((NMAXPIX + 255) / 256), dim3(256), 0, stream>>>(cur, out, NMAXPIX);
}

// Round 3
// 399.882 us; speedup vs baseline: 6.3835x; 1.5180x over previous
//
#include <hip/hip_runtime.h>
#include <stdint.h>

#define HID 256
#define NMAXPIX (1025 * 1025)
#define NREP 32        // histogram replicas (kills same-address atomic serialization)
#define CHUNK_MAX 2304 // max selection window per block (LDS selidx)

// per-stage small-buffer layout (u32 units)
#define HISTA_OFF 0                       // 2048*32
#define HISTB_OFF 65536                   // 2048*32
#define HISTC_OFF 131072                  // 1024*32
#define SCAL_OFF  163840                  // 4 (padded 512)
#define BCNT_OFF  164352                  // 512
#define STAGE_U32 165376

// ---------------- MLP eval: float4 LDS weight reads (ds_read_b128) ----------------
__device__ __forceinline__ float mlp_eval4(float wx, float wy,
                                           const float4* __restrict__ w1x,
                                           const float4* __restrict__ w1y,
                                           const float4* __restrict__ vb1,
                                           const float4* __restrict__ vw2, float b2v) {
    const float C0 = (float)(0.5 / 1025.0);
    float cx = wx / 1025.0f + C0;
    float cy = wy / 1025.0f + C0;
    float px = cx * 2.0f - 1.0f;
    float py = cy * 2.0f - 1.0f;
    float a0 = 0.f, a1 = 0.f, a2 = 0.f, a3 = 0.f;
#pragma unroll 8
    for (int q = 0; q < HID / 4; ++q) {
        float4 a = w1x[q], b = w1y[q], c = vb1[q], d = vw2[q];
        float h0 = px * a.x + py * b.x + c.x;
        float h1 = px * a.y + py * b.y + c.y;
        float h2 = px * a.z + py * b.z + c.z;
        float h3 = px * a.w + py * b.w + c.w;
        h0 = h0 > 0.f ? h0 : 0.f;
        h1 = h1 > 0.f ? h1 : 0.f;
        h2 = h2 > 0.f ? h2 : 0.f;
        h3 = h3 > 0.f ? h3 : 0.f;
        a0 += h0 * d.x;
        a1 += h1 * d.y;
        a2 += h2 * d.z;
        a3 += h3 * d.w;
    }
    float x = ((a0 + a1) + (a2 + a3)) + b2v;
    float r;
    if (x >= 0.f) { r = 1.0f / (1.0f + expf(-x)); }
    else { float e = expf(x); r = e / (1.0f + e); }
    return r;
}

// ---------------- stage 0: dense 65x65 eval ----------------
__global__ __launch_bounds__(256) void k_eval0(const float* __restrict__ w1, const float* __restrict__ b1,
                                               const float* __restrict__ w2, const float* __restrict__ b2,
                                               float* __restrict__ occ) {
    __shared__ alignas(16) float sw1[2 * HID];
    __shared__ alignas(16) float sb1[HID];
    __shared__ alignas(16) float sw2[HID];
    int tid = threadIdx.x;
    for (int i = tid; i < 2 * HID; i += 256) sw1[i] = w1[i];
    sb1[tid] = b1[tid];
    sw2[tid] = w2[tid];
    __syncthreads();
    int n = blockIdx.x * 256 + tid;
    if (n >= 65 * 65) return;
    int i = n / 65, j = n % 65;
    occ[n] = mlp_eval4(16.0f * (float)j, 16.0f * (float)i,
                       (const float4*)sw1, (const float4*)(sw1 + HID),
                       (const float4*)sb1, (const float4*)sw2, b2[0]);
}

// ---------------- upsample 2x (bitwise dyadic averages) + key + 11-bit msb hist ----------------
__global__ __launch_bounds__(256) void k_upkey(const float* __restrict__ in, int rp,
                                               float* __restrict__ out, int r,
                                               uint32_t* __restrict__ keys,
                                               uint32_t* __restrict__ histA) {
    __shared__ uint32_t hist[2048];
    int tid = threadIdx.x;
    for (int k = tid; k < 2048; k += 256) hist[k] = 0;
    __syncthreads();
    int n = blockIdx.x * 256 + tid;
    int N = r * r;
    bool act = n < N;
    uint32_t key = 0;
    if (act) {
        int i = n / r, j = n % r;
        int i2 = i >> 1, j2 = j >> 1;
        float v;
        if ((i & 1) == 0) {
            if ((j & 1) == 0) {
                v = in[i2 * rp + j2];
            } else {
                float a = in[i2 * rp + j2], b = in[i2 * rp + j2 + 1];
                v = a * 0.5f + b * 0.5f;
            }
        } else {
            if ((j & 1) == 0) {
                float a = in[i2 * rp + j2], b = in[(i2 + 1) * rp + j2];
                v = a * 0.5f + b * 0.5f;
            } else {
                float a = in[i2 * rp + j2],     c = in[i2 * rp + j2 + 1];
                float b = in[(i2 + 1) * rp + j2], d = in[(i2 + 1) * rp + j2 + 1];
                float t1 = a * 0.5f + b * 0.5f;
                float t2 = c * 0.5f + d * 0.5f;
                v = t1 * 0.5f + t2 * 0.5f;
            }
        }
        out[n] = v;
        float unc = -fabsf(v - 0.5f);
        uint32_t u = __float_as_uint(unc);
        key = (u & 0x80000000u) ? ~u : (u | 0x80000000u);
        keys[n] = key;
    }
    // wave-aggregated LDS histogram (kills -0.5 plateau contention)
    uint32_t bin = key >> 21;
    unsigned long long m = __ballot(act);
    if (m) {
        int leader = __ffsll(m) - 1;
        uint32_t lbin = (uint32_t)__shfl((int)bin, leader, 64);
        unsigned long long sm = __ballot(act && bin == lbin);
        int lane = tid & 63;
        if (sm == m) {
            if (lane == leader) atomicAdd(&hist[lbin], (uint32_t)__popcll(m));
        } else if (act) {
            atomicAdd(&hist[bin], 1u);
        }
    }
    __syncthreads();
    int rep = blockIdx.x & (NREP - 1);
    for (int k = tid; k < 2048; k += 256) {
        uint32_t c = hist[k];
        if (c) atomicAdd(&histA[k * NREP + rep], c);
    }
}

// ---------------- block exclusive scan helper (256 threads) ----------------
__device__ __forceinline__ uint32_t block_exscan_256(uint32_t v, volatile uint32_t* lds4) {
    int lane = threadIdx.x & 63, w = threadIdx.x >> 6;
    uint32_t inc = v;
#pragma unroll
    for (int d = 1; d < 64; d <<= 1) {
        uint32_t o = (uint32_t)__shfl_up((int)inc, d, 64);
        if (lane >= d) inc += o;
    }
    if (lane == 63) lds4[w] = inc;
    __syncthreads();
    uint32_t woff = 0;
    for (int i = 0; i < w; ++i) woff += lds4[i];
    return woff + inc - v;
}

// ---------------- radix-select scan pass (1 block) ----------------
// scal layout: [0]=prefix [1]=rem [2]=K [3]=t
__global__ __launch_bounds__(256) void k_scan(const uint32_t* __restrict__ hist, int NB,
                                              uint32_t* __restrict__ scal,
                                              int first, uint32_t npt, int shift, int last) {
    __shared__ uint32_t lds4[4];
    int tid = threadIdx.x;
    uint32_t rem    = first ? npt : scal[1];
    uint32_t prefix = first ? 0u  : scal[0];
    int C = NB >> 8;  // bins per thread (8 or 4)
    uint32_t cnts[8];
    uint32_t s = 0;
    for (int k = 0; k < C; ++k) {
        int rb = tid * C + k;            // reversed bin index (descending value order)
        int bin = NB - 1 - rb;
        const uint4* p = (const uint4*)(hist + (size_t)bin * NREP);
        uint32_t c = 0;
#pragma unroll
        for (int q = 0; q < NREP / 4; ++q) {
            uint4 v = p[q];
            c += v.x + v.y + v.z + v.w;
        }
        cnts[k] = c;
        s += c;
    }
    uint32_t excl = block_exscan_256(s, lds4);  // contains __syncthreads (scal reads happen before)
    uint32_t run = excl;
    for (int k = 0; k < C; ++k) {
        uint32_t c = cnts[k];
        if (rem > run && rem <= run + c) {
            uint32_t bin = (uint32_t)(NB - 1 - (tid * C + k));
            uint32_t npfx = (prefix << shift) | bin;
            uint32_t nrem = rem - run;
            if (last) { scal[2] = npfx; scal[3] = nrem; }
            else      { scal[0] = npfx; scal[1] = nrem; }
        }
        run += c;
    }
}

// ---------------- filtered histogram passes 2,3: LDS hist + replicated flush ----------------
__global__ __launch_bounds__(256) void k_hist_f(const uint32_t* __restrict__ keys, int N,
                                                const uint32_t* __restrict__ scal,
                                                uint32_t* __restrict__ hist,
                                                int fshift, int bshift, uint32_t bmask) {
    __shared__ uint32_t lh[2048];
    int tid = threadIdx.x;
    for (int k = tid; k < 2048; k += 256) lh[k] = 0;
    uint32_t prefix = scal[0];
    __syncthreads();
    int stride = gridDim.x * 256;
    int lane = tid & 63;
    for (int base = blockIdx.x * 256; base < N; base += stride) {
        int n = base + tid;
        bool inb = n < N;
        uint32_t key = inb ? keys[n] : 0u;
        bool flt = inb && ((key >> fshift) == prefix);
        uint32_t bin = (key >> bshift) & bmask;
        unsigned long long m = __ballot(flt);
        if (m) {
            int leader = __ffsll(m) - 1;
            uint32_t lbin = (uint32_t)__shfl((int)bin, leader, 64);
            unsigned long long sm = __ballot(flt && bin == lbin);
            if (sm == m) {
                if (lane == leader) atomicAdd(&lh[lbin], (uint32_t)__popcll(m));
            } else if (flt) {
                atomicAdd(&lh[bin], 1u);
            }
        }
    }
    __syncthreads();
    int rep = blockIdx.x & (NREP - 1);
    for (int k = tid; k < 2048; k += 256) {
        uint32_t c = lh[k];
        if (c) atomicAdd(&hist[k * NREP + rep], c);
    }
}

// ---------------- per-block tie counts (contiguous chunks, index order) ----------------
__global__ __launch_bounds__(256) void k_tiecnt(const uint32_t* __restrict__ keys, int N,
                                                const uint32_t* __restrict__ scal,
                                                uint32_t* __restrict__ bcnt, int chunk) {
    __shared__ uint32_t wsum[4];
    uint32_t K = scal[2];
    int base = blockIdx.x * chunk;
    int tid = threadIdx.x, lane = tid & 63, w = tid >> 6;
    uint32_t cnt = 0;
    for (int i = 0; i < chunk; i += 256) {
        int n = base + i + tid;
        if (n < N && keys[n] == K) cnt++;
    }
#pragma unroll
    for (int d = 32; d; d >>= 1) cnt += (uint32_t)__shfl_down((int)cnt, d, 64);
    if (lane == 0) wsum[w] = cnt;
    __syncthreads();
    if (tid == 0) bcnt[blockIdx.x] = wsum[0] + wsum[1] + wsum[2] + wsum[3];
}

// ---------------- final: exact top-k select -> LDS compaction -> dense MLP eval ----------------
__global__ __launch_bounds__(256) void k_final(const uint32_t* __restrict__ keys, int N, int r, float stride,
                                               const uint32_t* __restrict__ scal,
                                               const uint32_t* __restrict__ bcnt,
                                               float* __restrict__ occ,
                                               const float* __restrict__ w1, const float* __restrict__ b1,
                                               const float* __restrict__ w2, const float* __restrict__ b2,
                                               int chunk) {
    __shared__ alignas(16) float sw1[2 * HID];
    __shared__ alignas(16) float sb1[HID];
    __shared__ alignas(16) float sw2[HID];
    __shared__ uint32_t iterw[4];
    __shared__ uint32_t sbase;   // exclusive tie prefix for this block
    __shared__ uint32_t selcnt;
    __shared__ uint32_t selidx[CHUNK_MAX];
    int tid = threadIdx.x;
    for (int i = tid; i < 2 * HID; i += 256) sw1[i] = w1[i];
    sb1[tid] = b1[tid];
    sw2[tid] = w2[tid];
    if (tid == 0) { sbase = 0; selcnt = 0; }
    __syncthreads();

    // self-computed exclusive prefix over bcnt[0..blockIdx)
    uint32_t partial = 0;
    for (int i = tid; i < (int)blockIdx.x; i += 256) partial += bcnt[i];
#pragma unroll
    for (int d = 32; d; d >>= 1) partial += (uint32_t)__shfl_down((int)partial, d, 64);
    if ((tid & 63) == 0 && partial) atomicAdd(&sbase, partial);
    __syncthreads();

    uint32_t K = scal[2], t = scal[3];
    int lane = tid & 63, w = tid >> 6;
    uint32_t running = sbase;
    int base = blockIdx.x * chunk;
    for (int i = 0; i < chunk; i += 256) {
        int n = base + i + tid;
        bool inb = n < N;
        uint32_t key = inb ? keys[n] : 0u;
        bool tie = inb && (key == K);
        unsigned long long m = __ballot(tie);
        if (lane == 0) iterw[w] = (uint32_t)__popcll(m);
        __syncthreads();
        uint32_t mybase = running;
        for (int ww = 0; ww < w; ++ww) mybase += iterw[ww];
        uint32_t tot = iterw[0] + iterw[1] + iterw[2] + iterw[3];
        uint32_t rank = mybase + (uint32_t)__popcll(m & ((1ull << lane) - 1ull));
        bool sel = inb && ((key > K) || (tie && rank < t));
        // wave-aggregated LDS compaction
        unsigned long long smk = __ballot(sel);
        if (smk) {
            int leader = __ffsll(smk) - 1;
            uint32_t wbase = 0;
            if (lane == leader) wbase = atomicAdd(&selcnt, (uint32_t)__popcll(smk));
            wbase = (uint32_t)__shfl((int)wbase, leader, 64);
            if (sel) selidx[wbase + (uint32_t)__popcll(smk & ((1ull << lane) - 1ull))] = (uint32_t)n;
        }
        running += tot;
        __syncthreads();
    }

    // dense eval over compacted list (no divergence, full wave utilization)
    uint32_t cnt = selcnt;
    float vb2 = b2[0];
    const float4* w1x = (const float4*)sw1;
    const float4* w1y = (const float4*)(sw1 + HID);
    const float4* vb1 = (const float4*)sb1;
    const float4* vw2 = (const float4*)sw2;
    for (uint32_t i = tid; i < cnt; i += 256) {
        int n = (int)selidx[i];
        int pi = n / r, pj = n % r;
        occ[n] = mlp_eval4(stride * (float)pj, stride * (float)pi, w1x, w1y, vb1, vw2, vb2);
    }
}

// ---------------- broadcast batch-0 grid to all 8 batches ----------------
__global__ __launch_bounds__(256) void k_bcast(const float* __restrict__ src, float* __restrict__ dst, int N) {
    int n = blockIdx.x * 256 + threadIdx.x;
    if (n >= N) return;
    float v = src[n];
#pragma unroll
    for (int k = 0; k < 8; ++k) dst[(size_t)k * N + n] = v;
}

extern "C" void kernel_launch(void* const* d_in, const int* in_sizes, int n_in,
                              void* d_out, int out_size, void* d_ws, size_t ws_size,
                              hipStream_t stream) {
    const float* w1 = (const float*)d_in[0];
    const float* b1 = (const float*)d_in[1];
    const float* w2 = (const float*)d_in[2];
    const float* b2 = (const float*)d_in[3];
    float* out = (float*)d_out;

    const size_t A = (((size_t)NMAXPIX * 4) + 255) & ~(size_t)255;  // one grid buffer, 256B aligned
    const size_t SMALL_BYTES = (size_t)4 * STAGE_U32 * 4;            // 4 stages
    const size_t need = 3 * A + SMALL_BYTES;

    char* base = (ws_size >= need) ? (char*)d_ws : (char*)d_out;  // d_out is 33.6MB >= ~15.3MB needed
    float* buf0 = (float*)(base);
    float* buf1 = (float*)(base + A);
    uint32_t* keys = (uint32_t*)(base + 2 * A);
    uint32_t* smallb = (uint32_t*)(base + 3 * A);

    hipMemsetAsync(smallb, 0, SMALL_BYTES, stream);

    // stage 0
    k_eval0<<<dim3((65 * 65 + 255) / 256), dim3(256), 0, stream>>>(w1, b1, w2, b2, buf0);

    const int res[5]  = {65, 129, 257, 513, 1025};
    const int npts[5] = {0, 4096, 16384, 65536, 262144};
    const int chunks[5] = {0, 256, 256, 768, 2304};  // nb2 = 66/259/343/457 (<=512)
    float* cur = buf0;
    float* nxt = buf1;
    for (int s = 1; s < 5; ++s) {
        int rp = res[s - 1], r = res[s];
        int N = r * r;
        uint32_t npt = (uint32_t)npts[s];
        uint32_t* sm    = smallb + (size_t)(s - 1) * STAGE_U32;
        uint32_t* histA = sm + HISTA_OFF;
        uint32_t* histB = sm + HISTB_OFF;
        uint32_t* histC = sm + HISTC_OFF;
        uint32_t* scal  = sm + SCAL_OFF;
        uint32_t* bcnt  = sm + BCNT_OFF;
        int nb1 = (N + 255) / 256;
        int nbh = nb1 < 512 ? nb1 : 512;
        const int chunk = chunks[s];
        int nb2 = (N + chunk - 1) / chunk;
        float stride = 1024.0f / (float)(r - 1);

        k_upkey<<<dim3(nb1), dim3(256), 0, stream>>>(cur, rp, nxt, r, keys, histA);
        k_scan<<<dim3(1), dim3(256), 0, stream>>>(histA, 2048, scal, 1, npt, 0, 0);
        k_hist_f<<<dim3(nbh), dim3(256), 0, stream>>>(keys, N, scal, histB, 21, 10, 0x7FFu);
        k_scan<<<dim3(1), dim3(256), 0, stream>>>(histB, 2048, scal, 0, 0u, 11, 0);
        k_hist_f<<<dim3(nbh), dim3(256), 0, stream>>>(keys, N, scal, histC, 10, 0, 0x3FFu);
        k_scan<<<dim3(1), dim3(256), 0, stream>>>(histC, 1024, scal, 0, 0u, 10, 1);
        k_tiecnt<<<dim3(nb2), dim3(256), 0, stream>>>(keys, N, scal, bcnt, chunk);
        k_final<<<dim3(nb2), dim3(256), 0, stream>>>(keys, N, r, stride, scal, bcnt, nxt,
                                                     w1, b1, w2, b2, chunk);
        float* tmp = cur; cur = nxt; nxt = tmp;
    }
    // after 4 swaps cur == buf0 (d_out offset 0 in fallback mode — bcast is read-before-write safe per thread)
    k_bcast<<<dim3((NMAXPIX + 255) / 256), dim3(256), 0, stream>>>(cur, out, NMAXPIX);
}

// Round 5
// 385.307 us; speedup vs baseline: 6.6250x; 1.0378x over previous
//
#include <hip/hip_runtime.h>
#include <stdint.h>

#define HID 256
#define NMAXPIX (1025 * 1025)
#define NREP 16   // histogram replicas (kills same-address atomic serialization)
#define NSEG 2048 // selection segments (one wave each; 512 blocks)

// per-stage small-buffer layout (u32 units)
#define HISTA_OFF 0          // 2048*16
#define HISTB_OFF 32768      // 2048*16
#define HISTC_OFF 65536      // 1024*16
#define SCAL_OFF  81920      // 4 (padded 64)
#define GTC_OFF   81984      // 2048
#define TIC_OFF   84032      // 2048
#define STAGE_U32 86080

// ---------------- MLP eval: float4 LDS weight reads ----------------
__device__ __forceinline__ float mlp_eval4(float wx, float wy,
                                           const float4* __restrict__ w1x,
                                           const float4* __restrict__ w1y,
                                           const float4* __restrict__ vb1,
                                           const float4* __restrict__ vw2, float b2v) {
    const float C0 = (float)(0.5 / 1025.0);
    float px = (wx / 1025.0f + C0) * 2.0f - 1.0f;
    float py = (wy / 1025.0f + C0) * 2.0f - 1.0f;
    float a0 = 0.f, a1 = 0.f, a2 = 0.f, a3 = 0.f;
#pragma unroll 8
    for (int q = 0; q < HID / 4; ++q) {
        float4 a = w1x[q], b = w1y[q], c = vb1[q], d = vw2[q];
        float h0 = px * a.x + py * b.x + c.x;
        float h1 = px * a.y + py * b.y + c.y;
        float h2 = px * a.z + py * b.z + c.z;
        float h3 = px * a.w + py * b.w + c.w;
        h0 = h0 > 0.f ? h0 : 0.f;
        h1 = h1 > 0.f ? h1 : 0.f;
        h2 = h2 > 0.f ? h2 : 0.f;
        h3 = h3 > 0.f ? h3 : 0.f;
        a0 += h0 * d.x;
        a1 += h1 * d.y;
        a2 += h2 * d.z;
        a3 += h3 * d.w;
    }
    float x = ((a0 + a1) + (a2 + a3)) + b2v;
    float r;
    if (x >= 0.f) { r = 1.0f / (1.0f + expf(-x)); }
    else { float e = expf(x); r = e / (1.0f + e); }
    return r;
}

// ---------------- stage 0: dense 65x65 eval ----------------
__global__ __launch_bounds__(256) void k_eval0(const float* __restrict__ w1, const float* __restrict__ b1,
                                               const float* __restrict__ w2, const float* __restrict__ b2,
                                               float* __restrict__ occ) {
    __shared__ alignas(16) float sw1[2 * HID];
    __shared__ alignas(16) float sb1[HID];
    __shared__ alignas(16) float sw2[HID];
    int tid = threadIdx.x;
    for (int i = tid; i < 2 * HID; i += 256) sw1[i] = w1[i];
    sb1[tid] = b1[tid];
    sw2[tid] = w2[tid];
    __syncthreads();
    int n = blockIdx.x * 256 + tid;
    if (n >= 65 * 65) return;
    int i = n / 65, j = n % 65;
    occ[n] = mlp_eval4(16.0f * (float)j, 16.0f * (float)i,
                       (const float4*)sw1, (const float4*)(sw1 + HID),
                       (const float4*)sb1, (const float4*)sw2, b2[0]);
}

// ---------------- upsample 2x (bitwise dyadic averages) + key + 11-bit msb hist ----------------
__global__ __launch_bounds__(256) void k_upkey(const float* __restrict__ in, int rp,
                                               float* __restrict__ out, int r,
                                               uint32_t* __restrict__ keys,
                                               uint32_t* __restrict__ histA) {
    __shared__ uint32_t hist[2048];
    int tid = threadIdx.x;
    for (int k = tid; k < 2048; k += 256) hist[k] = 0;
    __syncthreads();
    int n = blockIdx.x * 256 + tid;
    int N = r * r;
    bool act = n < N;
    uint32_t key = 0;
    if (act) {
        int i = n / r, j = n % r;
        int i2 = i >> 1, j2 = j >> 1;
        float v;
        if ((i & 1) == 0) {
            if ((j & 1) == 0) {
                v = in[i2 * rp + j2];
            } else {
                float a = in[i2 * rp + j2], b = in[i2 * rp + j2 + 1];
                v = a * 0.5f + b * 0.5f;
            }
        } else {
            if ((j & 1) == 0) {
                float a = in[i2 * rp + j2], b = in[(i2 + 1) * rp + j2];
                v = a * 0.5f + b * 0.5f;
            } else {
                float a = in[i2 * rp + j2],     c = in[i2 * rp + j2 + 1];
                float b = in[(i2 + 1) * rp + j2], d = in[(i2 + 1) * rp + j2 + 1];
                float t1 = a * 0.5f + b * 0.5f;
                float t2 = c * 0.5f + d * 0.5f;
                v = t1 * 0.5f + t2 * 0.5f;
            }
        }
        out[n] = v;
        float unc = -fabsf(v - 0.5f);
        uint32_t u = __float_as_uint(unc);
        key = (u & 0x80000000u) ? ~u : (u | 0x80000000u);
        keys[n] = key;
    }
    uint32_t bin = key >> 21;
    unsigned long long m = __ballot(act);
    if (m) {
        int leader = __ffsll(m) - 1;
        uint32_t lbin = (uint32_t)__shfl((int)bin, leader, 64);
        unsigned long long sm = __ballot(act && bin == lbin);
        int lane = tid & 63;
        if (sm == m) {
            if (lane == leader) atomicAdd(&hist[lbin], (uint32_t)__popcll(m));
        } else if (act) {
            atomicAdd(&hist[bin], 1u);
        }
    }
    __syncthreads();
    int rep = blockIdx.x & (NREP - 1);
    for (int k = tid; k < 2048; k += 256) {
        uint32_t c = hist[k];
        if (c) atomicAdd(&histA[k * NREP + rep], c);
    }
}

// ---------------- block exclusive scan helper (256 threads) ----------------
__device__ __forceinline__ uint32_t block_exscan_256(uint32_t v, volatile uint32_t* lds4) {
    int lane = threadIdx.x & 63, w = threadIdx.x >> 6;
    uint32_t inc = v;
#pragma unroll
    for (int d = 1; d < 64; d <<= 1) {
        uint32_t o = (uint32_t)__shfl_up((int)inc, d, 64);
        if (lane >= d) inc += o;
    }
    if (lane == 63) lds4[w] = inc;
    __syncthreads();
    uint32_t woff = 0;
    for (int i = 0; i < w; ++i) woff += lds4[i];
    return woff + inc - v;
}

// ---------------- radix-select scan pass (1 block) ----------------
// scal layout: [0]=prefix [1]=rem [2]=K [3]=t
__global__ __launch_bounds__(256) void k_scan(const uint32_t* __restrict__ hist, int NB,
                                              uint32_t* __restrict__ scal,
                                              int first, uint32_t npt, int shift, int last) {
    __shared__ uint32_t lds4[4];
    int tid = threadIdx.x;
    uint32_t rem    = first ? npt : scal[1];
    uint32_t prefix = first ? 0u  : scal[0];
    int C = NB >> 8;  // bins per thread (8 or 4)
    uint32_t cnts[8];
    uint32_t s = 0;
    for (int k = 0; k < C; ++k) {
        int rb = tid * C + k;            // reversed bin index (descending value order)
        int bin = NB - 1 - rb;
        const uint4* p = (const uint4*)(hist + (size_t)bin * NREP);
        uint32_t c = 0;
#pragma unroll
        for (int q = 0; q < NREP / 4; ++q) {
            uint4 v = p[q];
            c += v.x + v.y + v.z + v.w;
        }
        cnts[k] = c;
        s += c;
    }
    uint32_t excl = block_exscan_256(s, lds4);  // contains __syncthreads (scal reads happen before)
    uint32_t run = excl;
    for (int k = 0; k < C; ++k) {
        uint32_t c = cnts[k];
        if (rem > run && rem <= run + c) {
            uint32_t bin = (uint32_t)(NB - 1 - (tid * C + k));
            uint32_t npfx = (prefix << shift) | bin;
            uint32_t nrem = rem - run;
            if (last) { scal[2] = npfx; scal[3] = nrem; }
            else      { scal[0] = npfx; scal[1] = nrem; }
        }
        run += c;
    }
}

// ---------------- filtered histogram passes 2,3: LDS hist + replicated flush ----------------
__global__ __launch_bounds__(256) void k_hist_f(const uint32_t* __restrict__ keys, int N,
                                                const uint32_t* __restrict__ scal,
                                                uint32_t* __restrict__ hist,
                                                int fshift, int bshift, uint32_t bmask) {
    __shared__ uint32_t lh[2048];
    int tid = threadIdx.x;
    for (int k = tid; k < 2048; k += 256) lh[k] = 0;
    uint32_t prefix = scal[0];
    __syncthreads();
    int stride = gridDim.x * 256;
    int lane = tid & 63;
    for (int base = blockIdx.x * 256; base < N; base += stride) {
        int n = base + tid;
        bool inb = n < N;
        uint32_t key = inb ? keys[n] : 0u;
        bool flt = inb && ((key >> fshift) == prefix);
        uint32_t bin = (key >> bshift) & bmask;
        unsigned long long m = __ballot(flt);
        if (m) {
            int leader = __ffsll(m) - 1;
            uint32_t lbin = (uint32_t)__shfl((int)bin, leader, 64);
            unsigned long long sm = __ballot(flt && bin == lbin);
            if (sm == m) {
                if (lane == leader) atomicAdd(&lh[lbin], (uint32_t)__popcll(m));
            } else if (flt) {
                atomicAdd(&lh[bin], 1u);
            }
        }
    }
    __syncthreads();
    int rep = blockIdx.x & (NREP - 1);
    for (int k = tid; k < 2048; k += 256) {
        uint32_t c = lh[k];
        if (c) atomicAdd(&hist[k * NREP + rep], c);
    }
}

// ---------------- per-segment gt/tie counts (one wave per segment, sync-free) ----------------
__global__ __launch_bounds__(256) void k_segcnt(const uint32_t* __restrict__ keys, int N, int seglen,
                                                const uint32_t* __restrict__ scal,
                                                uint32_t* __restrict__ gtc, uint32_t* __restrict__ tic) {
    int wv = blockIdx.x * 4 + (threadIdx.x >> 6);
    int lane = threadIdx.x & 63;
    uint32_t K = scal[2];
    int s0 = wv * seglen;
    int s1 = s0 + seglen; if (s1 > N) s1 = N;
    uint32_t g = 0, t = 0;
    for (int base = s0; base < s1; base += 64) {
        int n = base + lane;
        if (n < s1) {
            uint32_t k = keys[n];
            g += (k > K) ? 1u : 0u;
            t += (k == K) ? 1u : 0u;
        }
    }
#pragma unroll
    for (int d = 32; d; d >>= 1) {
        g += (uint32_t)__shfl_down((int)g, d, 64);
        t += (uint32_t)__shfl_down((int)t, d, 64);
    }
    if (lane == 0) { gtc[wv] = g; tic[wv] = t; }
}

// ---------------- select: atomic-free, sync-free compaction into global list ----------------
__global__ __launch_bounds__(256) void k_select(const uint32_t* __restrict__ keys, int N, int seglen,
                                                const uint32_t* __restrict__ scal,
                                                const uint32_t* __restrict__ gtc,
                                                const uint32_t* __restrict__ tic,
                                                uint32_t* __restrict__ outlist) {
    int wv = blockIdx.x * 4 + (threadIdx.x >> 6);
    int lane = threadIdx.x & 63;
    uint32_t K = scal[2], t = scal[3];
    // exclusive prefixes over segments [0, wv)
    uint32_t gp = 0, tp = 0;
    for (int i = lane; i < wv; i += 64) { gp += gtc[i]; tp += tic[i]; }
#pragma unroll
    for (int d = 32; d; d >>= 1) {
        gp += (uint32_t)__shfl_down((int)gp, d, 64);
        tp += (uint32_t)__shfl_down((int)tp, d, 64);
    }
    gp = (uint32_t)__shfl((int)gp, 0, 64);
    tp = (uint32_t)__shfl((int)tp, 0, 64);
    uint32_t acc_tie_before = tp < t ? tp : t;
    uint32_t outbase = gp + acc_tie_before;
    uint32_t tie_run = tp;
    int s0 = wv * seglen;
    int s1 = s0 + seglen; if (s1 > N) s1 = N;
    unsigned long long lowmask = (lane == 63) ? ~0ull >> 1 : ((1ull << lane) - 1ull);
    for (int base = s0; base < s1; base += 64) {
        int n = base + lane;
        bool inb = n < s1;
        uint32_t key = inb ? keys[n] : 0u;
        bool gt = inb && (key > K);
        bool tie = inb && (key == K);
        unsigned long long tm = __ballot(tie);
        uint32_t trank = tie_run + (uint32_t)__popcll(tm & lowmask);
        bool sel = gt || (tie && trank < t);
        unsigned long long sm = __ballot(sel);
        if (sel) outlist[outbase + (uint32_t)__popcll(sm & lowmask)] = (uint32_t)n;
        outbase += (uint32_t)__popcll(sm);
        tie_run += (uint32_t)__popcll(tm);
    }
}

// ---------------- dense eval of compacted list: 4 points per thread, weights reused ----------------
__global__ __launch_bounds__(256) void k_evalpts(const uint32_t* __restrict__ outlist, int r, float stride,
                                                 float* __restrict__ occ,
                                                 const float* __restrict__ w1, const float* __restrict__ b1,
                                                 const float* __restrict__ w2, const float* __restrict__ b2) {
    __shared__ alignas(16) float sw1[2 * HID];
    __shared__ alignas(16) float sb1[HID];
    __shared__ alignas(16) float sw2[HID];
    int tid = threadIdx.x;
    for (int i = tid; i < 2 * HID; i += 256) sw1[i] = w1[i];
    sb1[tid] = b1[tid];
    sw2[tid] = w2[tid];
    __syncthreads();
    const float4* w1x = (const float4*)sw1;
    const float4* w1y = (const float4*)(sw1 + HID);
    const float4* vb1 = (const float4*)sb1;
    const float4* vw2 = (const float4*)sw2;
    float vb2 = b2[0];
    const float C0 = (float)(0.5 / 1025.0);

    int gid = blockIdx.x * 256 + tid;
    uint4 nn = ((const uint4*)outlist)[gid];   // npt is a multiple of 1024 -> no tail
    uint32_t n0 = nn.x, n1 = nn.y, n2 = nn.z, n3 = nn.w;
    float px0, py0, px1, py1, px2, py2, px3, py3;
    {
        int i0 = (int)n0 / r, j0 = (int)n0 % r;
        int i1 = (int)n1 / r, j1 = (int)n1 % r;
        int i2 = (int)n2 / r, j2 = (int)n2 % r;
        int i3 = (int)n3 / r, j3 = (int)n3 % r;
        px0 = ((stride * (float)j0) / 1025.0f + C0) * 2.0f - 1.0f;
        py0 = ((stride * (float)i0) / 1025.0f + C0) * 2.0f - 1.0f;
        px1 = ((stride * (float)j1) / 1025.0f + C0) * 2.0f - 1.0f;
        py1 = ((stride * (float)i1) / 1025.0f + C0) * 2.0f - 1.0f;
        px2 = ((stride * (float)j2) / 1025.0f + C0) * 2.0f - 1.0f;
        py2 = ((stride * (float)i2) / 1025.0f + C0) * 2.0f - 1.0f;
        px3 = ((stride * (float)j3) / 1025.0f + C0) * 2.0f - 1.0f;
        py3 = ((stride * (float)i3) / 1025.0f + C0) * 2.0f - 1.0f;
    }
    float4 A0 = {0, 0, 0, 0}, A1 = {0, 0, 0, 0}, A2 = {0, 0, 0, 0}, A3 = {0, 0, 0, 0};
#pragma unroll 4
    for (int q = 0; q < HID / 4; ++q) {
        float4 a = w1x[q], b = w1y[q], c = vb1[q], d = vw2[q];
#define STEP(P, AX) {                                              \
        float h0 = px##P * a.x + py##P * b.x + c.x;                \
        float h1 = px##P * a.y + py##P * b.y + c.y;                \
        float h2 = px##P * a.z + py##P * b.z + c.z;                \
        float h3 = px##P * a.w + py##P * b.w + c.w;                \
        h0 = h0 > 0.f ? h0 : 0.f;                                  \
        h1 = h1 > 0.f ? h1 : 0.f;                                  \
        h2 = h2 > 0.f ? h2 : 0.f;                                  \
        h3 = h3 > 0.f ? h3 : 0.f;                                  \
        AX.x += h0 * d.x; AX.y += h1 * d.y;                        \
        AX.z += h2 * d.z; AX.w += h3 * d.w; }
        STEP(0, A0) STEP(1, A1) STEP(2, A2) STEP(3, A3)
#undef STEP
    }
#define FIN(P, AX, NP) {                                           \
        float x = ((AX.x + AX.y) + (AX.z + AX.w)) + vb2;           \
        float rr;                                                  \
        if (x >= 0.f) { rr = 1.0f / (1.0f + expf(-x)); }           \
        else { float e = expf(x); rr = e / (1.0f + e); }           \
        occ[NP] = rr; }
    FIN(0, A0, n0) FIN(1, A1, n1) FIN(2, A2, n2) FIN(3, A3, n3)
#undef FIN
}

// ---------------- broadcast batch-0 grid to all 8 batches (float4) ----------------
__global__ __launch_bounds__(256) void k_bcast(const float* __restrict__ src, float* __restrict__ dst, int N) {
    int q = blockIdx.x * 256 + threadIdx.x;
    int n = q * 4;
    if (n + 3 < N) {
        float4 v = *(const float4*)(src + n);
#pragma unroll
        for (int k = 0; k < 8; ++k) *(float4*)(dst + (size_t)k * N + n) = v;
    } else if (n < N) {
        for (int m = n; m < N; ++m) {
            float v = src[m];
#pragma unroll
            for (int k = 0; k < 8; ++k) dst[(size_t)k * N + m] = v;
        }
    }
}

extern "C" void kernel_launch(void* const* d_in, const int* in_sizes, int n_in,
                              void* d_out, int out_size, void* d_ws, size_t ws_size,
                              hipStream_t stream) {
    const float* w1 = (const float*)d_in[0];
    const float* b1 = (const float*)d_in[1];
    const float* w2 = (const float*)d_in[2];
    const float* b2 = (const float*)d_in[3];
    float* out = (float*)d_out;

    const size_t A = (((size_t)NMAXPIX * 4) + 255) & ~(size_t)255;  // one grid buffer
    const size_t SMALL_BYTES = (size_t)4 * STAGE_U32 * 4;            // 4 stages
    const size_t LIST_BYTES = (size_t)262144 * 4;
    const size_t need = 3 * A + SMALL_BYTES + LIST_BYTES;

    char* base = (ws_size >= need) ? (char*)d_ws : (char*)d_out;  // d_out 33.6MB >= ~15MB needed
    float* buf0 = (float*)(base);
    float* buf1 = (float*)(base + A);
    uint32_t* keys = (uint32_t*)(base + 2 * A);
    uint32_t* smallb = (uint32_t*)(base + 3 * A);
    uint32_t* outlist = (uint32_t*)(base + 3 * A + SMALL_BYTES);

    hipMemsetAsync(smallb, 0, SMALL_BYTES, stream);

    // stage 0
    k_eval0<<<dim3((65 * 65 + 255) / 256), dim3(256), 0, stream>>>(w1, b1, w2, b2, buf0);

    const int res[5]  = {65, 129, 257, 513, 1025};
    const int npts[5] = {0, 4096, 16384, 65536, 262144};
    float* cur = buf0;
    float* nxt = buf1;
    for (int s = 1; s < 5; ++s) {
        int rp = res[s - 1], r = res[s];
        int N = r * r;
        uint32_t npt = (uint32_t)npts[s];
        uint32_t* sm    = smallb + (size_t)(s - 1) * STAGE_U32;
        uint32_t* histA = sm + HISTA_OFF;
        uint32_t* histB = sm + HISTB_OFF;
        uint32_t* histC = sm + HISTC_OFF;
        uint32_t* scal  = sm + SCAL_OFF;
        uint32_t* gtc   = sm + GTC_OFF;
        uint32_t* tic   = sm + TIC_OFF;
        int nb1 = (N + 255) / 256;
        int nbh = nb1 < 512 ? nb1 : 512;
        int seglen = (N + NSEG - 1) / NSEG;
        float stride = 1024.0f / (float)(r - 1);

        k_upkey<<<dim3(nb1), dim3(256), 0, stream>>>(cur, rp, nxt, r, keys, histA);
        k_scan<<<dim3(1), dim3(256), 0, stream>>>(histA, 2048, scal, 1, npt, 0, 0);
        k_hist_f<<<dim3(nbh), dim3(256), 0, stream>>>(keys, N, scal, histB, 21, 10, 0x7FFu);
        k_scan<<<dim3(1), dim3(256), 0, stream>>>(histB, 2048, scal, 0, 0u, 11, 0);
        k_hist_f<<<dim3(nbh), dim3(256), 0, stream>>>(keys, N, scal, histC, 10, 0, 0x3FFu);
        k_scan<<<dim3(1), dim3(256), 0, stream>>>(histC, 1024, scal, 0, 0u, 10, 1);
        k_segcnt<<<dim3(NSEG / 4), dim3(256), 0, stream>>>(keys, N, seglen, scal, gtc, tic);
        k_select<<<dim3(NSEG / 4), dim3(256), 0, stream>>>(keys, N, seglen, scal, gtc, tic, outlist);
        k_evalpts<<<dim3(npt / 1024), dim3(256), 0, stream>>>(outlist, r, stride, nxt, w1, b1, w2, b2);
        float* tmp = cur; cur = nxt; nxt = tmp;
    }
    // after 4 swaps cur == buf0 (d_out offset 0 in fallback mode — bcast batch-0 writes are identity)
    // grid: ceil(ceil(NMAXPIX/4)/256) — R4 bug: floor here dropped the last pixel (tail thread never launched)
    k_bcast<<<dim3(((NMAXPIX + 3) / 4 + 255) / 256), dim3(256), 0, stream>>>(cur, out, NMAXPIX);
}

// Round 6
// 332.550 us; speedup vs baseline: 7.6760x; 1.1586x over previous
//
#include <hip/hip_runtime.h>
#include <stdint.h>

#define HID 256
#define NMAXPIX (1025 * 1025)
#define NREP 16   // histogram replicas, REPLICA-MAJOR: hist[rep*NBINS+bin] (distinct cache lines!)
#define NSEG 2048 // selection segments (one wave each; 512 blocks)

// per-stage small-buffer layout (u32 units)
#define HISTA_OFF 0          // 16 reps x 2048
#define HISTB_OFF 32768      // 16 reps x 2048
#define HISTC_OFF 65536      // 16 reps x 1024
#define SCAL_OFF  81920      // 4 (padded 64)
#define GTC_OFF   81984      // 2048
#define TIC_OFF   84032      // 2048
#define STAGE_U32 86080

// ---------------- MLP eval: float4 LDS weight reads ----------------
__device__ __forceinline__ float mlp_eval4(float wx, float wy,
                                           const float4* __restrict__ w1x,
                                           const float4* __restrict__ w1y,
                                           const float4* __restrict__ vb1,
                                           const float4* __restrict__ vw2, float b2v) {
    const float C0 = (float)(0.5 / 1025.0);
    float px = (wx / 1025.0f + C0) * 2.0f - 1.0f;
    float py = (wy / 1025.0f + C0) * 2.0f - 1.0f;
    float a0 = 0.f, a1 = 0.f, a2 = 0.f, a3 = 0.f;
#pragma unroll 8
    for (int q = 0; q < HID / 4; ++q) {
        float4 a = w1x[q], b = w1y[q], c = vb1[q], d = vw2[q];
        float h0 = px * a.x + py * b.x + c.x;
        float h1 = px * a.y + py * b.y + c.y;
        float h2 = px * a.z + py * b.z + c.z;
        float h3 = px * a.w + py * b.w + c.w;
        h0 = h0 > 0.f ? h0 : 0.f;
        h1 = h1 > 0.f ? h1 : 0.f;
        h2 = h2 > 0.f ? h2 : 0.f;
        h3 = h3 > 0.f ? h3 : 0.f;
        a0 += h0 * d.x;
        a1 += h1 * d.y;
        a2 += h2 * d.z;
        a3 += h3 * d.w;
    }
    float x = ((a0 + a1) + (a2 + a3)) + b2v;
    float r;
    if (x >= 0.f) { r = 1.0f / (1.0f + expf(-x)); }
    else { float e = expf(x); r = e / (1.0f + e); }
    return r;
}

// ---------------- stage 0: dense 65x65 eval ----------------
__global__ __launch_bounds__(256) void k_eval0(const float* __restrict__ w1, const float* __restrict__ b1,
                                               const float* __restrict__ w2, const float* __restrict__ b2,
                                               float* __restrict__ occ) {
    __shared__ alignas(16) float sw1[2 * HID];
    __shared__ alignas(16) float sb1[HID];
    __shared__ alignas(16) float sw2[HID];
    int tid = threadIdx.x;
    for (int i = tid; i < 2 * HID; i += 256) sw1[i] = w1[i];
    sb1[tid] = b1[tid];
    sw2[tid] = w2[tid];
    __syncthreads();
    int n = blockIdx.x * 256 + tid;
    if (n >= 65 * 65) return;
    int i = n / 65, j = n % 65;
    occ[n] = mlp_eval4(16.0f * (float)j, 16.0f * (float)i,
                       (const float4*)sw1, (const float4*)(sw1 + HID),
                       (const float4*)sb1, (const float4*)sw2, b2[0]);
}

// ---------------- upsample 2x + key + 11-bit msb hist (grid-stride, <=1024 blocks) ----------------
__global__ __launch_bounds__(256) void k_upkey(const float* __restrict__ in, int rp,
                                               float* __restrict__ out, int r,
                                               uint32_t* __restrict__ keys,
                                               uint32_t* __restrict__ histA) {
    __shared__ uint32_t hist[2048];
    int tid = threadIdx.x;
    for (int k = tid; k < 2048; k += 256) hist[k] = 0;
    __syncthreads();
    int N = r * r;
    int lane = tid & 63;
    int gstride = gridDim.x * 256;
    for (int n0 = blockIdx.x * 256; n0 < N; n0 += gstride) {
        int n = n0 + tid;
        bool act = n < N;
        uint32_t key = 0;
        if (act) {
            int i = n / r, j = n % r;
            int i2 = i >> 1, j2 = j >> 1;
            float v;
            if ((i & 1) == 0) {
                if ((j & 1) == 0) {
                    v = in[i2 * rp + j2];
                } else {
                    float a = in[i2 * rp + j2], b = in[i2 * rp + j2 + 1];
                    v = a * 0.5f + b * 0.5f;
                }
            } else {
                if ((j & 1) == 0) {
                    float a = in[i2 * rp + j2], b = in[(i2 + 1) * rp + j2];
                    v = a * 0.5f + b * 0.5f;
                } else {
                    float a = in[i2 * rp + j2],     c = in[i2 * rp + j2 + 1];
                    float b = in[(i2 + 1) * rp + j2], d = in[(i2 + 1) * rp + j2 + 1];
                    float t1 = a * 0.5f + b * 0.5f;
                    float t2 = c * 0.5f + d * 0.5f;
                    v = t1 * 0.5f + t2 * 0.5f;
                }
            }
            out[n] = v;
            float unc = -fabsf(v - 0.5f);
            uint32_t u = __float_as_uint(unc);
            key = (u & 0x80000000u) ? ~u : (u | 0x80000000u);
            keys[n] = key;
        }
        uint32_t bin = key >> 21;
        unsigned long long m = __ballot(act);
        if (m) {
            int leader = __ffsll(m) - 1;
            uint32_t lbin = (uint32_t)__shfl((int)bin, leader, 64);
            unsigned long long sm = __ballot(act && bin == lbin);
            if (sm == m) {
                if (lane == leader) atomicAdd(&hist[lbin], (uint32_t)__popcll(m));
            } else if (act) {
                atomicAdd(&hist[bin], 1u);
            }
        }
    }
    __syncthreads();
    // replica-major flush: each replica region is 8KB -> different blocks hit different lines
    uint32_t* myrep = histA + (size_t)(blockIdx.x & (NREP - 1)) * 2048;
    for (int k = tid; k < 2048; k += 256) {
        uint32_t c = hist[k];
        if (c) atomicAdd(&myrep[k], c);
    }
}

// ---------------- block exclusive scan helper (256 threads) ----------------
__device__ __forceinline__ uint32_t block_exscan_256(uint32_t v, volatile uint32_t* lds4) {
    int lane = threadIdx.x & 63, w = threadIdx.x >> 6;
    uint32_t inc = v;
#pragma unroll
    for (int d = 1; d < 64; d <<= 1) {
        uint32_t o = (uint32_t)__shfl_up((int)inc, d, 64);
        if (lane >= d) inc += o;
    }
    if (lane == 63) lds4[w] = inc;
    __syncthreads();
    uint32_t woff = 0;
    for (int i = 0; i < w; ++i) woff += lds4[i];
    return woff + inc - v;
}

// ---------------- radix-select scan pass (1 block) ----------------
// scal layout: [0]=prefix [1]=rem [2]=K [3]=t
__global__ __launch_bounds__(256) void k_scan(const uint32_t* __restrict__ hist, int NB,
                                              uint32_t* __restrict__ scal,
                                              int first, uint32_t npt, int shift, int last) {
    __shared__ uint32_t lds4[4];
    int tid = threadIdx.x;
    uint32_t rem    = first ? npt : scal[1];
    uint32_t prefix = first ? 0u  : scal[0];
    int C = NB >> 8;  // bins per thread (8 or 4)
    // thread's ascending contiguous bin range [b0, b0+C); thread 0 owns the TOP bins
    int b0 = NB - (tid + 1) * C;
    uint32_t cnts[8];
#pragma unroll
    for (int k = 0; k < 8; ++k) cnts[k] = 0;
    for (int rep = 0; rep < NREP; ++rep) {
        const uint4* p = (const uint4*)(hist + (size_t)rep * NB + b0);
#pragma unroll
        for (int g = 0; g < 2; ++g) {
            if (g * 4 < C) {
                uint4 v = p[g];
                cnts[g * 4 + 0] += v.x;
                cnts[g * 4 + 1] += v.y;
                cnts[g * 4 + 2] += v.z;
                cnts[g * 4 + 3] += v.w;
            }
        }
    }
    uint32_t s = 0;
    for (int k = 0; k < C; ++k) s += cnts[k];
    uint32_t excl = block_exscan_256(s, lds4);  // contains __syncthreads (scal reads happen before)
    // walk thread's bins in DESCENDING bin order: bin = b0+C-1-k  (== NB-1-tid*C-k, same as before)
    uint32_t run = excl;
    for (int k = 0; k < C; ++k) {
        uint32_t c = cnts[C - 1 - k];
        if (rem > run && rem <= run + c) {
            uint32_t bin = (uint32_t)(b0 + C - 1 - k);
            uint32_t npfx = (prefix << shift) | bin;
            uint32_t nrem = rem - run;
            if (last) { scal[2] = npfx; scal[3] = nrem; }
            else      { scal[0] = npfx; scal[1] = nrem; }
        }
        run += c;
    }
}

// ---------------- filtered histogram passes 2,3: LDS hist + replica-major flush ----------------
__global__ __launch_bounds__(256) void k_hist_f(const uint32_t* __restrict__ keys, int N,
                                                const uint32_t* __restrict__ scal,
                                                uint32_t* __restrict__ hist, int NB,
                                                int fshift, int bshift, uint32_t bmask) {
    __shared__ uint32_t lh[2048];
    int tid = threadIdx.x;
    for (int k = tid; k < 2048; k += 256) lh[k] = 0;
    uint32_t prefix = scal[0];
    __syncthreads();
    int stride = gridDim.x * 256;
    int lane = tid & 63;
    for (int base = blockIdx.x * 256; base < N; base += stride) {
        int n = base + tid;
        bool inb = n < N;
        uint32_t key = inb ? keys[n] : 0u;
        bool flt = inb && ((key >> fshift) == prefix);
        uint32_t bin = (key >> bshift) & bmask;
        unsigned long long m = __ballot(flt);
        if (m) {
            int leader = __ffsll(m) - 1;
            uint32_t lbin = (uint32_t)__shfl((int)bin, leader, 64);
            unsigned long long sm = __ballot(flt && bin == lbin);
            if (sm == m) {
                if (lane == leader) atomicAdd(&lh[lbin], (uint32_t)__popcll(m));
            } else if (flt) {
                atomicAdd(&lh[bin], 1u);
            }
        }
    }
    __syncthreads();
    uint32_t* myrep = hist + (size_t)(blockIdx.x & (NREP - 1)) * NB;
    for (int k = tid; k < NB; k += 256) {
        uint32_t c = lh[k];
        if (c) atomicAdd(&myrep[k], c);
    }
}

// ---------------- per-segment gt/tie counts (one wave per segment, sync-free) ----------------
__global__ __launch_bounds__(256) void k_segcnt(const uint32_t* __restrict__ keys, int N, int seglen,
                                                const uint32_t* __restrict__ scal,
                                                uint32_t* __restrict__ gtc, uint32_t* __restrict__ tic) {
    int wv = blockIdx.x * 4 + (threadIdx.x >> 6);
    int lane = threadIdx.x & 63;
    uint32_t K = scal[2];
    int s0 = wv * seglen;
    int s1 = s0 + seglen; if (s1 > N) s1 = N;
    uint32_t g = 0, t = 0;
    for (int base = s0; base < s1; base += 64) {
        int n = base + lane;
        if (n < s1) {
            uint32_t k = keys[n];
            g += (k > K) ? 1u : 0u;
            t += (k == K) ? 1u : 0u;
        }
    }
#pragma unroll
    for (int d = 32; d; d >>= 1) {
        g += (uint32_t)__shfl_down((int)g, d, 64);
        t += (uint32_t)__shfl_down((int)t, d, 64);
    }
    if (lane == 0) { gtc[wv] = g; tic[wv] = t; }
}

// ---------------- select: atomic-free, sync-free compaction into global list ----------------
__global__ __launch_bounds__(256) void k_select(const uint32_t* __restrict__ keys, int N, int seglen,
                                                const uint32_t* __restrict__ scal,
                                                const uint32_t* __restrict__ gtc,
                                                const uint32_t* __restrict__ tic,
                                                uint32_t* __restrict__ outlist) {
    int wv = blockIdx.x * 4 + (threadIdx.x >> 6);
    int lane = threadIdx.x & 63;
    uint32_t K = scal[2], t = scal[3];
    // exclusive prefixes over segments [0, wv)
    uint32_t gp = 0, tp = 0;
    for (int i = lane; i < wv; i += 64) { gp += gtc[i]; tp += tic[i]; }
#pragma unroll
    for (int d = 32; d; d >>= 1) {
        gp += (uint32_t)__shfl_down((int)gp, d, 64);
        tp += (uint32_t)__shfl_down((int)tp, d, 64);
    }
    gp = (uint32_t)__shfl((int)gp, 0, 64);
    tp = (uint32_t)__shfl((int)tp, 0, 64);
    uint32_t acc_tie_before = tp < t ? tp : t;
    uint32_t outbase = gp + acc_tie_before;
    uint32_t tie_run = tp;
    int s0 = wv * seglen;
    int s1 = s0 + seglen; if (s1 > N) s1 = N;
    unsigned long long lowmask = (lane == 63) ? ~0ull >> 1 : ((1ull << lane) - 1ull);
    for (int base = s0; base < s1; base += 64) {
        int n = base + lane;
        bool inb = n < s1;
        uint32_t key = inb ? keys[n] : 0u;
        bool gt = inb && (key > K);
        bool tie = inb && (key == K);
        unsigned long long tm = __ballot(tie);
        uint32_t trank = tie_run + (uint32_t)__popcll(tm & lowmask);
        bool sel = gt || (tie && trank < t);
        unsigned long long sm = __ballot(sel);
        if (sel) outlist[outbase + (uint32_t)__popcll(sm & lowmask)] = (uint32_t)n;
        outbase += (uint32_t)__popcll(sm);
        tie_run += (uint32_t)__popcll(tm);
    }
}

// ---------------- dense eval of compacted list: 4 points per thread, weights reused ----------------
__global__ __launch_bounds__(256) void k_evalpts(const uint32_t* __restrict__ outlist, int r, float stride,
                                                 float* __restrict__ occ,
                                                 const float* __restrict__ w1, const float* __restrict__ b1,
                                                 const float* __restrict__ w2, const float* __restrict__ b2) {
    __shared__ alignas(16) float sw1[2 * HID];
    __shared__ alignas(16) float sb1[HID];
    __shared__ alignas(16) float sw2[HID];
    int tid = threadIdx.x;
    for (int i = tid; i < 2 * HID; i += 256) sw1[i] = w1[i];
    sb1[tid] = b1[tid];
    sw2[tid] = w2[tid];
    __syncthreads();
    const float4* w1x = (const float4*)sw1;
    const float4* w1y = (const float4*)(sw1 + HID);
    const float4* vb1 = (const float4*)sb1;
    const float4* vw2 = (const float4*)sw2;
    float vb2 = b2[0];
    const float C0 = (float)(0.5 / 1025.0);

    int gid = blockIdx.x * 256 + tid;
    uint4 nn = ((const uint4*)outlist)[gid];   // npt is a multiple of 1024 -> no tail
    uint32_t n0 = nn.x, n1 = nn.y, n2 = nn.z, n3 = nn.w;
    float px0, py0, px1, py1, px2, py2, px3, py3;
    {
        int i0 = (int)n0 / r, j0 = (int)n0 % r;
        int i1 = (int)n1 / r, j1 = (int)n1 % r;
        int i2 = (int)n2 / r, j2 = (int)n2 % r;
        int i3 = (int)n3 / r, j3 = (int)n3 % r;
        px0 = ((stride * (float)j0) / 1025.0f + C0) * 2.0f - 1.0f;
        py0 = ((stride * (float)i0) / 1025.0f + C0) * 2.0f - 1.0f;
        px1 = ((stride * (float)j1) / 1025.0f + C0) * 2.0f - 1.0f;
        py1 = ((stride * (float)i1) / 1025.0f + C0) * 2.0f - 1.0f;
        px2 = ((stride * (float)j2) / 1025.0f + C0) * 2.0f - 1.0f;
        py2 = ((stride * (float)i2) / 1025.0f + C0) * 2.0f - 1.0f;
        px3 = ((stride * (float)j3) / 1025.0f + C0) * 2.0f - 1.0f;
        py3 = ((stride * (float)i3) / 1025.0f + C0) * 2.0f - 1.0f;
    }
    float4 A0 = {0, 0, 0, 0}, A1 = {0, 0, 0, 0}, A2 = {0, 0, 0, 0}, A3 = {0, 0, 0, 0};
#pragma unroll 4
    for (int q = 0; q < HID / 4; ++q) {
        float4 a = w1x[q], b = w1y[q], c = vb1[q], d = vw2[q];
#define STEP(P, AX) {                                              \
        float h0 = px##P * a.x + py##P * b.x + c.x;                \
        float h1 = px##P * a.y + py##P * b.y + c.y;                \
        float h2 = px##P * a.z + py##P * b.z + c.z;                \
        float h3 = px##P * a.w + py##P * b.w + c.w;                \
        h0 = h0 > 0.f ? h0 : 0.f;                                  \
        h1 = h1 > 0.f ? h1 : 0.f;                                  \
        h2 = h2 > 0.f ? h2 : 0.f;                                  \
        h3 = h3 > 0.f ? h3 : 0.f;                                  \
        AX.x += h0 * d.x; AX.y += h1 * d.y;                        \
        AX.z += h2 * d.z; AX.w += h3 * d.w; }
        STEP(0, A0) STEP(1, A1) STEP(2, A2) STEP(3, A3)
#undef STEP
    }
#define FIN(P, AX, NP) {                                           \
        float x = ((AX.x + AX.y) + (AX.z + AX.w)) + vb2;           \
        float rr;                                                  \
        if (x >= 0.f) { rr = 1.0f / (1.0f + expf(-x)); }           \
        else { float e = expf(x); rr = e / (1.0f + e); }           \
        occ[NP] = rr; }
    FIN(0, A0, n0) FIN(1, A1, n1) FIN(2, A2, n2) FIN(3, A3, n3)
#undef FIN
}

// ---------------- broadcast batch-0 grid to all 8 batches (float4) ----------------
__global__ __launch_bounds__(256) void k_bcast(const float* __restrict__ src, float* __restrict__ dst, int N) {
    int q = blockIdx.x * 256 + threadIdx.x;
    int n = q * 4;
    if (n + 3 < N) {
        float4 v = *(const float4*)(src + n);
#pragma unroll
        for (int k = 0; k < 8; ++k) *(float4*)(dst + (size_t)k * N + n) = v;
    } else if (n < N) {
        for (int m = n; m < N; ++m) {
            float v = src[m];
#pragma unroll
            for (int k = 0; k < 8; ++k) dst[(size_t)k * N + m] = v;
        }
    }
}

extern "C" void kernel_launch(void* const* d_in, const int* in_sizes, int n_in,
                              void* d_out, int out_size, void* d_ws, size_t ws_size,
                              hipStream_t stream) {
    const float* w1 = (const float*)d_in[0];
    const float* b1 = (const float*)d_in[1];
    const float* w2 = (const float*)d_in[2];
    const float* b2 = (const float*)d_in[3];
    float* out = (float*)d_out;

    const size_t A = (((size_t)NMAXPIX * 4) + 255) & ~(size_t)255;  // one grid buffer
    const size_t SMALL_BYTES = (size_t)4 * STAGE_U32 * 4;            // 4 stages
    const size_t LIST_BYTES = (size_t)262144 * 4;
    const size_t need = 3 * A + SMALL_BYTES + LIST_BYTES;

    char* base = (ws_size >= need) ? (char*)d_ws : (char*)d_out;  // d_out 33.6MB >= ~15MB needed
    float* buf0 = (float*)(base);
    float* buf1 = (float*)(base + A);
    uint32_t* keys = (uint32_t*)(base + 2 * A);
    uint32_t* smallb = (uint32_t*)(base + 3 * A);
    uint32_t* outlist = (uint32_t*)(base + 3 * A + SMALL_BYTES);

    hipMemsetAsync(smallb, 0, SMALL_BYTES, stream);

    // stage 0
    k_eval0<<<dim3((65 * 65 + 255) / 256), dim3(256), 0, stream>>>(w1, b1, w2, b2, buf0);

    const int res[5]  = {65, 129, 257, 513, 1025};
    const int npts[5] = {0, 4096, 16384, 65536, 262144};
    float* cur = buf0;
    float* nxt = buf1;
    for (int s = 1; s < 5; ++s) {
        int rp = res[s - 1], r = res[s];
        int N = r * r;
        uint32_t npt = (uint32_t)npts[s];
        uint32_t* sm    = smallb + (size_t)(s - 1) * STAGE_U32;
        uint32_t* histA = sm + HISTA_OFF;
        uint32_t* histB = sm + HISTB_OFF;
        uint32_t* histC = sm + HISTC_OFF;
        uint32_t* scal  = sm + SCAL_OFF;
        uint32_t* gtc   = sm + GTC_OFF;
        uint32_t* tic   = sm + TIC_OFF;
        int nb1 = (N + 255) / 256;
        int nbu = nb1 < 1024 ? nb1 : 1024;   // k_upkey grid-stride cap (flush atomics scale with blocks)
        int nbh = nb1 < 512 ? nb1 : 512;
        int seglen = (N + NSEG - 1) / NSEG;
        float stride = 1024.0f / (float)(r - 1);

        k_upkey<<<dim3(nbu), dim3(256), 0, stream>>>(cur, rp, nxt, r, keys, histA);
        k_scan<<<dim3(1), dim3(256), 0, stream>>>(histA, 2048, scal, 1, npt, 0, 0);
        k_hist_f<<<dim3(nbh), dim3(256), 0, stream>>>(keys, N, scal, histB, 2048, 21, 10, 0x7FFu);
        k_scan<<<dim3(1), dim3(256), 0, stream>>>(histB, 2048, scal, 0, 0u, 11, 0);
        k_hist_f<<<dim3(nbh), dim3(256), 0, stream>>>(keys, N, scal, histC, 1024, 10, 0, 0x3FFu);
        k_scan<<<dim3(1), dim3(256), 0, stream>>>(histC, 1024, scal, 0, 0u, 10, 1);
        k_segcnt<<<dim3(NSEG / 4), dim3(256), 0, stream>>>(keys, N, seglen, scal, gtc, tic);
        k_select<<<dim3(NSEG / 4), dim3(256), 0, stream>>>(keys, N, seglen, scal, gtc, tic, outlist);
        k_evalpts<<<dim3(npt / 1024), dim3(256), 0, stream>>>(outlist, r, stride, nxt, w1, b1, w2, b2);
        float* tmp = cur; cur = nxt; nxt = tmp;
    }
    // after 4 swaps cur == buf0 (d_out offset 0 in fallback mode — bcast batch-0 writes are identity)
    k_bcast<<<dim3(((NMAXPIX + 3) / 4 + 255) / 256), dim3(256), 0, stream>>>(cur, out, NMAXPIX);
}